// Round 20
// baseline (230.940 us; speedup 1.0000x reference)
//
#include <hip/hip_runtime.h>
#include <hip/hip_bf16.h>
#include <math.h>

#define BDIM 1024
#define HEADS 16
#define HDIM 64
#define LSEQ 2048
#define NBATCH 2
#define DFFDIM 4096
#define QKVN 3072
#define LOG2E 1.44269504f

typedef __bf16 bf16x8_t __attribute__((ext_vector_type(8)));
typedef float f32x4_t __attribute__((ext_vector_type(4)));

__device__ __forceinline__ ushort f2bf(float f) {
    union { __hip_bfloat16 b; ushort u; } cv;
    cv.b = __float2bfloat16(f);
    return cv.u;
}
__device__ __forceinline__ float bf2f(ushort u) {
    union { unsigned int i; float f; } cv;
    cv.i = ((unsigned int)u) << 16;
    return cv.f;
}

// ---------------- transpose + fp32->bf16 convert: Wt[n][k] = bf16(W[k][n]) ----
__global__ __launch_bounds__(256) void transpose_cvt(const float* __restrict__ W,
                                                     ushort* __restrict__ Wt,
                                                     int K, int N) {
    __shared__ ushort tile[32][33];
    int bi = blockIdx.y;   // K / 32
    int bj = blockIdx.x;   // N / 32
    int tx = threadIdx.x;  // 32
    int ty = threadIdx.y;  // 8
#pragma unroll
    for (int r = 0; r < 4; ++r) {
        int krow = bi * 32 + ty + r * 8;
        int ncol = bj * 32 + tx;
        tile[ty + r * 8][tx] = f2bf(W[(size_t)krow * N + ncol]);
    }
    __syncthreads();
#pragma unroll
    for (int r = 0; r < 4; ++r) {
        int nrow = bj * 32 + ty + r * 8;
        int kcol = bi * 32 + tx;
        Wt[(size_t)nrow * K + kcol] = tile[tx][ty + r * 8];
    }
}

// ---------------- batched 4x 1024x1024 transpose (one dispatch) ---------------
__global__ __launch_bounds__(256) void transpose_cvt4(const float* __restrict__ W0,
                                                      const float* __restrict__ W1,
                                                      const float* __restrict__ W2,
                                                      const float* __restrict__ W3,
                                                      ushort* __restrict__ T0,
                                                      ushort* __restrict__ T1,
                                                      ushort* __restrict__ T2,
                                                      ushort* __restrict__ T3) {
    __shared__ ushort tile[32][33];
    const int z = blockIdx.z;
    const float* W = z == 0 ? W0 : z == 1 ? W1 : z == 2 ? W2 : W3;
    ushort* T = z == 0 ? T0 : z == 1 ? T1 : z == 2 ? T2 : T3;
    int bi = blockIdx.y, bj = blockIdx.x;
    int tx = threadIdx.x, ty = threadIdx.y;
#pragma unroll
    for (int r = 0; r < 4; ++r)
        tile[ty + r * 8][tx] = f2bf(W[(size_t)(bi * 32 + ty + r * 8) * 1024 + bj * 32 + tx]);
    __syncthreads();
#pragma unroll
    for (int r = 0; r < 4; ++r)
        T[(size_t)(bj * 32 + ty + r * 8) * 1024 + bi * 32 + tx] = tile[tx][ty + r * 8];
}

// ---------------- RMSNorm: fp32 in -> bf16 out --------------------------------
__global__ __launch_bounds__(256) void rmsnorm_k(const float* __restrict__ x,
                                                 const float* __restrict__ g,
                                                 ushort* __restrict__ out) {
    int row = blockIdx.x;
    int t = threadIdx.x;
    int w = t >> 6, l = t & 63;
    const float4 v = reinterpret_cast<const float4*>(x + (size_t)row * BDIM)[t];
    float ss = v.x * v.x + v.y * v.y + v.z * v.z + v.w * v.w;
#pragma unroll
    for (int m = 1; m <= 32; m <<= 1) ss += __shfl_xor(ss, m);
    __shared__ float wsum[4];
    if (l == 0) wsum[w] = ss;
    __syncthreads();
    float tot = wsum[0] + wsum[1] + wsum[2] + wsum[3];
    float r = rsqrtf(tot * (1.0f / BDIM) + 1e-6f);
    const float4 gv = reinterpret_cast<const float4*>(g)[t];
    ushort4 o;
    o.x = f2bf(v.x * r * gv.x);
    o.y = f2bf(v.y * r * gv.y);
    o.z = f2bf(v.z * r * gv.z);
    o.w = f2bf(v.w * r * gv.w);
    reinterpret_cast<ushort4*>(out + (size_t)row * BDIM)[t] = o;
}

// ---------------- T5 bias table PRE-SCALED by log2e: btab[h][d] ---------------
__global__ void bias_table_k(const float* __restrict__ rel, float* __restrict__ btab) {
    int idx = blockIdx.x * 256 + threadIdx.x;
    if (idx >= HEADS * 4095) return;
    int h = idx / 4095;
    int d = idx % 4095;
    int rp = d - 2047;                 // mem - ctx
    int bucket = rp > 0 ? 16 : 0;
    int rpa = rp < 0 ? -rp : rp;
    if (rpa < 8) {
        bucket += rpa;
    } else {
        int large = 8 + (int)(logf((float)rpa * 0.125f) * (1.0f / logf(16.0f)) * 8.0f);
        bucket += large < 15 ? large : 15;
    }
    btab[idx] = rel[bucket * HEADS + h] * LOG2E;
}

// ---------------- split-K2 reduce + residual + RMSNorm ------------------------
__global__ __launch_bounds__(256) void reduce2_rms(const ushort* __restrict__ parts,
                                                   const float* __restrict__ res,
                                                   const float* __restrict__ g,
                                                   float* __restrict__ out,
                                                   ushort* __restrict__ hout,
                                                   size_t mn) {
    int row = blockIdx.x;
    int t = threadIdx.x;
    int w = t >> 6, l = t & 63;
    size_t i = (size_t)row * BDIM + t * 4;
    float4 r = *(const float4*)(res + i);
    ushort4 a = *(const ushort4*)(parts + i);
    ushort4 b = *(const ushort4*)(parts + mn + i);
    float4 o;
    o.x = r.x + bf2f(a.x) + bf2f(b.x);
    o.y = r.y + bf2f(a.y) + bf2f(b.y);
    o.z = r.z + bf2f(a.z) + bf2f(b.z);
    o.w = r.w + bf2f(a.w) + bf2f(b.w);
    *(float4*)(out + i) = o;
    float ss = o.x * o.x + o.y * o.y + o.z * o.z + o.w * o.w;
#pragma unroll
    for (int m = 1; m <= 32; m <<= 1) ss += __shfl_xor(ss, m);
    __shared__ float wsum[4];
    if (l == 0) wsum[w] = ss;
    __syncthreads();
    float tot = wsum[0] + wsum[1] + wsum[2] + wsum[3];
    float rr = rsqrtf(tot * (1.0f / BDIM) + 1e-6f);
    const float4 gv = reinterpret_cast<const float4*>(g)[t];
    ushort4 h;
    h.x = f2bf(o.x * rr * gv.x);
    h.y = f2bf(o.y * rr * gv.y);
    h.z = f2bf(o.z * rr * gv.z);
    h.w = f2bf(o.w * rr * gv.w);
    reinterpret_cast<ushort4*>(hout + (size_t)row * BDIM)[t] = h;
}

// ---------------- split-K4 reduce: out = res + sum of 4 bf16 partials ---------
__global__ __launch_bounds__(256) void reduce4_k(const ushort* __restrict__ p01,
                                                 const ushort* __restrict__ p23,
                                                 const float* __restrict__ res,
                                                 float* __restrict__ out,
                                                 size_t mn) {
    size_t i = ((size_t)blockIdx.x * 256 + threadIdx.x) * 4;
    float4 r = *(const float4*)(res + i);
    ushort4 a = *(const ushort4*)(p01 + i);
    ushort4 b = *(const ushort4*)(p01 + mn + i);
    ushort4 c = *(const ushort4*)(p23 + i);
    ushort4 d = *(const ushort4*)(p23 + mn + i);
    float4 o;
    o.x = r.x + bf2f(a.x) + bf2f(b.x) + bf2f(c.x) + bf2f(d.x);
    o.y = r.y + bf2f(a.y) + bf2f(b.y) + bf2f(c.y) + bf2f(d.y);
    o.z = r.z + bf2f(a.z) + bf2f(b.z) + bf2f(c.z) + bf2f(d.z);
    o.w = r.w + bf2f(a.w) + bf2f(b.w) + bf2f(c.w) + bf2f(d.w);
    *(float4*)(out + i) = o;
}

// ---------------- bf16 GEMM, B pre-transposed (Bt is N x K), 1D grid + XCD swz
// m97 single-buffer 2-barrier structure + T2 swizzle. Optional split-K.
// MODE 0: bf16 ; MODE 1: f32 res+ ; MODE 2: relu ; MODE 3: bf16 partial ;
// MODE 4: QKV fused-vtrans (V cols transposed into vtb; Q cols scaled by log2e)
template <int MODE, int TM, int TN>
__global__ __launch_bounds__(256) void gemm_bt(const ushort* __restrict__ A,
                                               const ushort* __restrict__ Bt,
                                               void* Cout, const float* res,
                                               ushort* __restrict__ vtb,
                                               int M, int N, int K, int nbx, int nkc) {
    __shared__ __align__(16) ushort As[TM * 64];
    __shared__ __align__(16) ushort Bs[TN * 64];
    constexpr int MF = TM / 32, NF = TN / 32;
    const int nwg = gridDim.x;
    const int bid = blockIdx.x;
    const int swz = (bid & 7) * (nwg >> 3) + (bid >> 3);   // nwg % 8 == 0 always
    const int nxy = nwg / nkc;
    const int chunk = swz / nxy;
    const int bxy = swz % nxy;
    const int bx = bxy % nbx, by = bxy / nbx;
    const int Kc = K / nkc;
    const int kbeg = chunk * Kc;
    const int tid = threadIdx.x;
    const int w = tid >> 6, l = tid & 63;
    const int wm = w >> 1, wn = w & 1;
    const int rowA0 = by * TM;
    const int colB0 = bx * TN;
    const int lr = l >> 3;
    const int scs = ((l & 7) ^ lr) * 8;        // pre-swizzled source col (ushorts)
    const int c = l & 15, gq = l >> 4;
    const int rswz = (c & 7) * 8;              // read-side XOR (row&7 == c&7)
    f32x4_t acc[MF][NF] = {};

    auto stage = [&](int k0) {
#pragma unroll
        for (int i = 0; i < TM / 32; ++i) {
            int r = i * 32 + w * 8;
            __builtin_amdgcn_global_load_lds(
                (const __attribute__((address_space(1))) uint32_t*)(A + (size_t)(rowA0 + r + lr) * K + kbeg + k0 + scs),
                (__attribute__((address_space(3))) uint32_t*)(&As[r * 64]), 16, 0, 0);
        }
#pragma unroll
        for (int i = 0; i < TN / 32; ++i) {
            int r = i * 32 + w * 8;
            __builtin_amdgcn_global_load_lds(
                (const __attribute__((address_space(1))) uint32_t*)(Bt + (size_t)(colB0 + r + lr) * K + kbeg + k0 + scs),
                (__attribute__((address_space(3))) uint32_t*)(&Bs[r * 64]), 16, 0, 0);
        }
    };

    const int nk = Kc >> 6;
    for (int kt = 0; kt < nk; ++kt) {
        __syncthreads();           // previous tile's readers done
        stage(kt << 6);
        __syncthreads();           // vmcnt drained: tile visible
#pragma unroll
        for (int kk = 0; kk < 2; ++kk) {
            bf16x8_t av[MF], bv[NF];
#pragma unroll
            for (int mf = 0; mf < MF; ++mf)
                av[mf] = *(const bf16x8_t*)&As[(wm * (TM / 2) + mf * 16 + c) * 64 + ((kk * 32 + gq * 8) ^ rswz)];
#pragma unroll
            for (int nf = 0; nf < NF; ++nf)
                bv[nf] = *(const bf16x8_t*)&Bs[(wn * (TN / 2) + nf * 16 + c) * 64 + ((kk * 32 + gq * 8) ^ rswz)];
#pragma unroll
            for (int mf = 0; mf < MF; ++mf)
#pragma unroll
                for (int nf = 0; nf < NF; ++nf)
                    acc[mf][nf] = __builtin_amdgcn_mfma_f32_16x16x32_bf16(av[mf], bv[nf], acc[mf][nf], 0, 0, 0);
        }
    }
    if (MODE == 4 && colB0 >= 2048) {
        // V block: store transposed into vtb[(b*16+h)*64+hd][key]
#pragma unroll
        for (int mf = 0; mf < MF; ++mf) {
#pragma unroll
            for (int nf = 0; nf < NF; ++nf) {
                int col = colB0 + wn * (TN / 2) + nf * 16 + c;
                int v = col - 2048;
                int hh = v >> 6, hd = v & 63;
                int row0 = rowA0 + wm * (TM / 2) + mf * 16 + gq * 4;
                int bb = row0 >> 11, key = row0 & 2047;
                ushort4 ov;
                ov.x = f2bf(acc[mf][nf][0]);
                ov.y = f2bf(acc[mf][nf][1]);
                ov.z = f2bf(acc[mf][nf][2]);
                ov.w = f2bf(acc[mf][nf][3]);
                *(ushort4*)(vtb + ((size_t)((bb * 16 + hh) * 64 + hd)) * 2048 + key) = ov;
            }
        }
        return;
    }
#pragma unroll
    for (int mf = 0; mf < MF; ++mf) {
#pragma unroll
        for (int nf = 0; nf < NF; ++nf) {
#pragma unroll
            for (int i = 0; i < 4; ++i) {
                int row = rowA0 + wm * (TM / 2) + mf * 16 + gq * 4 + i;
                int col = colB0 + wn * (TN / 2) + nf * 16 + c;
                size_t idx = (size_t)row * N + col;
                float vv = acc[mf][nf][i];
                if (MODE == 0 || MODE == 4) {
                    if (MODE == 4 && col < 1024) vv *= LOG2E;   // pre-scale Q for exp2 softmax
                    ((ushort*)Cout)[idx] = f2bf(vv);
                } else if (MODE == 1) {
                    ((float*)Cout)[idx] = res[idx] + vv;
                } else if (MODE == 2) {
                    ((ushort*)Cout)[idx] = f2bf(vv > 0.f ? vv : 0.f);
                } else {
                    ((ushort*)Cout)[(size_t)chunk * M * N + idx] = f2bf(vv);
                }
            }
        }
    }
}

// ---------------- 8-phase 256x256 GEMM (T3+T4+T5), 8 waves, 128KB LDS ---------
// Next-tile staging front-loaded into phases 0/1 so the K-tile-boundary
// vmcnt(0) has >= 2 phases of compute cover. MODE 2: relu; MODE 3: split-K
// partials (chunks 0,1 -> Cout, chunks 2,3 -> Cout2).
template <int MODE>
__global__ __launch_bounds__(512, 1) void gemm_bt8(const ushort* __restrict__ A,
                                                   const ushort* __restrict__ Bt,
                                                   void* Cout, void* Cout2,
                                                   int M, int N, int K, int nbx, int nkc) {
    __shared__ __align__(16) ushort As[2][256 * 64];
    __shared__ __align__(16) ushort Bs[2][256 * 64];
    const int nwg = gridDim.x;
    const int bid = blockIdx.x;
    const int swz = (bid & 7) * (nwg >> 3) + (bid >> 3);
    const int nxy = nwg / nkc;
    const int chunk = swz / nxy;
    const int bxy = swz % nxy;
    const int bx = bxy % nbx, by = bxy / nbx;
    const int Kc = K / nkc;
    const int kbeg = chunk * Kc;
    const int tid = threadIdx.x;
    const int w = tid >> 6, l = tid & 63;
    const int wm = w >> 2, wn = w & 3;          // 2 x 4 wave grid
    const int rowA0 = by * 256, colB0 = bx * 256;
    const int st_r = tid >> 3;                  // 0..63 row within chunk
    const int scs = ((l & 7) ^ (st_r & 7)) * 8; // pre-swizzled source col
    const int c = l & 15, gq = l >> 4;
    const int rswz = (c & 7) * 8;
    f32x4_t acc[8][4] = {};

    auto stageChunk = [&](int buf, int k0, int q) {
        __builtin_amdgcn_global_load_lds(
            (const __attribute__((address_space(1))) uint32_t*)(A + (size_t)(rowA0 + q * 64 + st_r) * K + kbeg + k0 + scs),
            (__attribute__((address_space(3))) uint32_t*)(&As[buf][(q * 64 + w * 8) * 64]), 16, 0, 0);
        __builtin_amdgcn_global_load_lds(
            (const __attribute__((address_space(1))) uint32_t*)(Bt + (size_t)(colB0 + q * 64 + st_r) * K + kbeg + k0 + scs),
            (__attribute__((address_space(3))) uint32_t*)(&Bs[buf][(q * 64 + w * 8) * 64]), 16, 0, 0);
    };

    const int nk = Kc >> 6;
    stageChunk(0, 0, 0);
    stageChunk(0, 0, 1);
    stageChunk(0, 0, 2);
    stageChunk(0, 0, 3);
    asm volatile("s_waitcnt vmcnt(0)" ::: "memory");
    __builtin_amdgcn_s_barrier();
    __builtin_amdgcn_sched_barrier(0);

    for (int k = 0; k < nk; ++k) {
        const int cur = k & 1;
        const ushort* Ab = &As[cur][0];
        const ushort* Bb = &Bs[cur][0];
#pragma unroll
        for (int q = 0; q < 4; ++q) {
            const int mh = q >> 1, nh = q & 1;
            bf16x8_t av[4][2], bv[2][2];
#pragma unroll
            for (int mf = 0; mf < 4; ++mf)
#pragma unroll
                for (int kk = 0; kk < 2; ++kk)
                    av[mf][kk] = *(const bf16x8_t*)&Ab[(wm * 128 + mh * 64 + mf * 16 + c) * 64 + ((kk * 32 + gq * 8) ^ rswz)];
#pragma unroll
            for (int nf = 0; nf < 2; ++nf)
#pragma unroll
                for (int kk = 0; kk < 2; ++kk)
                    bv[nf][kk] = *(const bf16x8_t*)&Bb[(wn * 64 + nh * 32 + nf * 16 + c) * 64 + ((kk * 32 + gq * 8) ^ rswz)];
            if (k + 1 < nk) {
                if (q == 0) { stageChunk(cur ^ 1, (k + 1) << 6, 0); stageChunk(cur ^ 1, (k + 1) << 6, 1); }
                else if (q == 1) { stageChunk(cur ^ 1, (k + 1) << 6, 2); stageChunk(cur ^ 1, (k + 1) << 6, 3); }
            }
            __builtin_amdgcn_s_barrier();
            __builtin_amdgcn_sched_barrier(0);
            __builtin_amdgcn_s_setprio(1);
#pragma unroll
            for (int kk = 0; kk < 2; ++kk)
#pragma unroll
                for (int mf = 0; mf < 4; ++mf)
#pragma unroll
                    for (int nf = 0; nf < 2; ++nf)
                        acc[mh * 4 + mf][nh * 2 + nf] = __builtin_amdgcn_mfma_f32_16x16x32_bf16(
                            av[mf][kk], bv[nf][kk], acc[mh * 4 + mf][nh * 2 + nf], 0, 0, 0);
            __builtin_amdgcn_s_setprio(0);
            if (q == 3 && k + 1 < nk)
                asm volatile("s_waitcnt vmcnt(0)" ::: "memory");
            __builtin_amdgcn_s_barrier();
            __builtin_amdgcn_sched_barrier(0);
        }
    }
    ushort* dst;
    if (MODE == 3)
        dst = (ushort*)(chunk < 2 ? Cout : Cout2) + (size_t)(chunk & 1) * M * N;
    else
        dst = (ushort*)Cout;
#pragma unroll
    for (int am = 0; am < 8; ++am) {
#pragma unroll
        for (int an = 0; an < 4; ++an) {
#pragma unroll
            for (int i = 0; i < 4; ++i) {
                int row = rowA0 + wm * 128 + am * 16 + gq * 4 + i;
                int col = colB0 + wn * 64 + an * 16 + c;
                size_t idx = (size_t)row * N + col;
                float vv = acc[am][an][i];
                if (MODE == 2) {
                    dst[idx] = f2bf(vv > 0.f ? vv : 0.f);
                } else {
                    dst[idx] = f2bf(vv);
                }
            }
        }
    }
}

// ---------------- flash attention: 4 waves x 32 q-rows, LDS dbuf, exp2 softmax
// Each wave owns TWO 16-row q-groups -> every K/V fragment read from LDS feeds
// 2 MFMAs (halves LDS-read bytes per q-row). Q/bias pre-scaled by log2e.
// grid: x = q-tile (L/128), y = b*H + h. block = 256 (4 waves).
__global__ __launch_bounds__(256) void attn_fwd(const ushort* __restrict__ qkv,
                                                const ushort* __restrict__ vT,
                                                const float* __restrict__ btab,
                                                ushort* __restrict__ ob) {
    const int tid = threadIdx.x, w = tid >> 6, l = tid & 63;
    const int bh = blockIdx.y, b = bh >> 4, h = bh & 15;
    const int qt = blockIdx.x;
    __shared__ __align__(16) ushort Ks[2][64 * 64];    // [key][hd ^ swz]
    __shared__ __align__(16) ushort Vs[2][64 * 64];    // [hd][key ^ swz]
    __shared__ __align__(16) ushort Pl[4][32 * 72];    // per-wave P[q(32)][key], stride 72
    const int q0 = qt * 128 + w * 32;                  // wave's 32 q-rows
    const int c = l & 15, g = l >> 4;
    const size_t rowbase = (size_t)b * LSEQ * QKVN;
    const ushort* qp = qkv + rowbase + h * HDIM;
    const ushort* kp = qkv + rowbase + BDIM + h * HDIM;
    const ushort* vtp = vT + (size_t)bh * HDIM * LSEQ;
    const int sr = w * 8 + (l >> 3);             // staging row within 32-row half
    const int scs = ((l & 7) ^ (l >> 3)) * 8;    // swizzled source col (ushorts)
    const float* btq4 = btab + h * 4095 + 2047 - (q0 + c) + g * 4;

    bf16x8_t aq[2][2];  // [qg][kk]: Q[q0 + qg*16 + c][kk*32 + g*8 + j] (log2e-scaled)
#pragma unroll
    for (int qg = 0; qg < 2; ++qg)
#pragma unroll
        for (int kk = 0; kk < 2; ++kk)
            aq[qg][kk] = *(const bf16x8_t*)(qp + (size_t)(q0 + qg * 16 + c) * QKVN + kk * 32 + g * 8);

    float lrow[2] = {0.f, 0.f};
    f32x4_t o[2][4] = {};   // [qg][hf]
    f32x4_t s[2][4];        // [qg][nf]

    auto stage = [&](int buf, int key0) {
#pragma unroll
        for (int i = 0; i < 2; ++i) {
            __builtin_amdgcn_global_load_lds(
                (const __attribute__((address_space(1))) uint32_t*)(kp + (size_t)(key0 + i * 32 + sr) * QKVN + scs),
                (__attribute__((address_space(3))) uint32_t*)(&Ks[buf][(i * 32 + w * 8) * 64]), 16, 0, 0);
            __builtin_amdgcn_global_load_lds(
                (const __attribute__((address_space(1))) uint32_t*)(vtp + (size_t)(i * 32 + sr) * LSEQ + key0 + scs),
                (__attribute__((address_space(3))) uint32_t*)(&Vs[buf][(i * 32 + w * 8) * 64]), 16, 0, 0);
        }
    };
    auto loadBias = [&](int key0) {
#pragma unroll
        for (int qg = 0; qg < 2; ++qg)
#pragma unroll
            for (int nf = 0; nf < 4; ++nf)
#pragma unroll
                for (int i = 0; i < 4; ++i)
                    s[qg][nf][i] = btq4[key0 + nf * 16 + i - qg * 16];
    };

    stage(0, 0);
    loadBias(0);
    int cur = 0;

    ushort* Pw = Pl[w];
    const int rswz = (c & 7) << 3;   // read-side XOR for rows nf*16+c / hf*16+c
    for (int kt = 0; kt < 32; ++kt) {
        __syncthreads();   // buf[cur] staged (vmcnt drained at barrier); buf[cur^1] free
        if (kt < 31) stage(cur ^ 1, kt * 64 + 64);
        // 1. S^T = bias + K Q^T for BOTH q-groups (K frag read once)
#pragma unroll
        for (int kk = 0; kk < 2; ++kk)
#pragma unroll
            for (int nf = 0; nf < 4; ++nf) {
                bf16x8_t kf = *(const bf16x8_t*)&Ks[cur][(nf * 16 + c) * 64 + ((kk * 32 + g * 8) ^ rswz)];
                s[0][nf] = __builtin_amdgcn_mfma_f32_16x16x32_bf16(kf, aq[0][kk], s[0][nf], 0, 0, 0);
                s[1][nf] = __builtin_amdgcn_mfma_f32_16x16x32_bf16(kf, aq[1][kk], s[1][nf], 0, 0, 0);
            }
        // 2. P = exp2(s), per-lane row-sums; P -> per-wave LDS
#pragma unroll
        for (int qg = 0; qg < 2; ++qg) {
            float rs = 0.f;
            union { ushort us[4]; uint2 u2; } pk[4];
#pragma unroll
            for (int nf = 0; nf < 4; ++nf)
#pragma unroll
                for (int i = 0; i < 4; ++i) {
                    float pv = __builtin_amdgcn_exp2f(s[qg][nf][i]);
                    rs += pv;
                    pk[nf].us[i] = f2bf(pv);
                }
            lrow[qg] += rs;
#pragma unroll
            for (int nf = 0; nf < 4; ++nf)
                *(uint2*)&Pw[(qg * 16 + c) * 72 + nf * 16 + g * 4] = pk[nf].u2;
        }
        // 3. prefetch bias(kt+1) into accumulators (s dead; L1-resident)
        if (kt < 31) loadBias(kt * 64 + 64);
        bf16x8_t pa[2][2];
#pragma unroll
        for (int qg = 0; qg < 2; ++qg)
#pragma unroll
            for (int kk = 0; kk < 2; ++kk)
                pa[qg][kk] = *(const bf16x8_t*)&Pw[(qg * 16 + c) * 72 + kk * 32 + g * 8];
        // 4. O^T += V^T P^T for BOTH q-groups (V frag read once)
#pragma unroll
        for (int kk = 0; kk < 2; ++kk)
#pragma unroll
            for (int hf = 0; hf < 4; ++hf) {
                bf16x8_t vf = *(const bf16x8_t*)&Vs[cur][(hf * 16 + c) * 64 + ((kk * 32 + g * 8) ^ rswz)];
                o[0][hf] = __builtin_amdgcn_mfma_f32_16x16x32_bf16(vf, pa[0][kk], o[0][hf], 0, 0, 0);
                o[1][hf] = __builtin_amdgcn_mfma_f32_16x16x32_bf16(vf, pa[1][kk], o[1][hf], 0, 0, 0);
            }
        cur ^= 1;
    }
    // deferred cross-lane row-sums + output
#pragma unroll
    for (int qg = 0; qg < 2; ++qg) {
        float lr = lrow[qg];
        lr += __shfl_xor(lr, 16);
        lr += __shfl_xor(lr, 32);
        const float inv = 1.f / lr;
        ushort* orow = ob + (size_t)(b * LSEQ + q0 + qg * 16 + c) * BDIM + h * HDIM + g * 4;
#pragma unroll
        for (int hf = 0; hf < 4; ++hf) {
            ushort4 ov;
            ov.x = f2bf(o[qg][hf][0] * inv);
            ov.y = f2bf(o[qg][hf][1] * inv);
            ov.z = f2bf(o[qg][hf][2] * inv);
            ov.w = f2bf(o[qg][hf][3] * inv);
            *(ushort4*)(orow + hf * 16) = ov;
        }
    }
}

extern "C" void kernel_launch(void* const* d_in, const int* in_sizes, int n_in,
                              void* d_out, int out_size, void* d_ws, size_t ws_size,
                              hipStream_t stream) {
    const float* x   = (const float*)d_in[0];
    const float* Wq  = (const float*)d_in[1];
    const float* Wk  = (const float*)d_in[2];
    const float* Wv  = (const float*)d_in[3];
    const float* Wo  = (const float*)d_in[4];
    const float* W1  = (const float*)d_in[5];
    const float* W2  = (const float*)d_in[6];
    const float* g1  = (const float*)d_in[7];
    const float* g2  = (const float*)d_in[8];
    const float* rel = (const float*)d_in[9];
    float* out = (float*)d_out;

    char* ws = (char*)d_ws;
    const size_t MB = 1024 * 1024;
    ushort* wqkvT = (ushort*)(ws + 0 * MB);    // 6MB (dead after QKV)
    ushort* woT   = (ushort*)(ws + 6 * MB);    // 2MB (dead after Wo gemm)
    ushort* w1T   = (ushort*)(ws + 8 * MB);    // 8MB (dead after FF1)
    ushort* w2T   = (ushort*)(ws + 16 * MB);   // 8MB (live through W2 gemm)
    float*  btab  = (float*)(ws + 24 * MB);    // 256KB
    ushort* hbuf  = (ushort*)(ws + 25 * MB);   // 8MB: h, then attn_out, then h2
    ushort* qkvb  = (ushort*)(ws + 33 * MB);   // 24MB (dead after attn)
    ushort* woP   = (ushort*)(ws + 33 * MB);   // 16MB Wo partials (over dead qkv)
    ushort* f1b   = (ushort*)(ws + 33 * MB);   // 32MB FF1 out (33-65)
    ushort* vTb   = (ushort*)(ws + 57 * MB);   // 8MB (dead after attn)
    ushort* w2P0  = (ushort*)(ws + 0 * MB);    // 16MB W2 partials 0,1 (dead weights)
    ushort* w2P1  = (ushort*)(ws + 65 * MB);   // 16MB W2 partials 2,3 (65-81)
    (void)in_sizes; (void)n_in; (void)out_size; (void)ws_size;

    const size_t MN = (size_t)4096 * 1024;
    dim3 tb(32, 8);
    transpose_cvt4<<<dim3(32, 32, 4), tb, 0, stream>>>(Wq, Wk, Wv, Wo,
        wqkvT, wqkvT + 1024 * 1024, wqkvT + 2048 * 1024, woT);
    transpose_cvt<<<dim3(128, 32), tb, 0, stream>>>(W1, w1T, 1024, 4096);
    transpose_cvt<<<dim3(32, 128), tb, 0, stream>>>(W2, w2T, 4096, 1024);
    bias_table_k<<<256, 256, 0, stream>>>(rel, btab);

    rmsnorm_k<<<4096, 256, 0, stream>>>(x, g1, hbuf);
    // QKV: 4096 x 3072 x 1024, 128x128 -> 768 blocks; V transposed, Q pre-scaled
    gemm_bt<4, 128, 128><<<768, 256, 0, stream>>>(hbuf, wqkvT, qkvb, nullptr, vTb, 4096, QKVN, 1024, 24, 1);
    attn_fwd<<<dim3(16, 32), 256, 0, stream>>>(qkvb, vTb, btab, hbuf);
    // Wo: 4096 x 1024 x 1024, 128x128, split-K=2 -> 512 blocks
    gemm_bt<3, 128, 128><<<512, 256, 0, stream>>>(hbuf, woT, woP, nullptr, nullptr, 4096, 1024, 1024, 8, 2);
    // fused: out = x + sum(partials); hbuf = rmsnorm(out)*g2
    reduce2_rms<<<4096, 256, 0, stream>>>(woP, x, g2, out, hbuf, MN);
    // FF1: 4096 x 4096 x 1024, 256x256 8-phase -> 256 blocks (1/CU), relu -> bf16
    gemm_bt8<2><<<256, 512, 0, stream>>>(hbuf, w1T, f1b, nullptr, 4096, DFFDIM, 1024, 16, 1);
    // W2: 4096 x 1024 x 4096, 256x256 8-phase, split-K=4 -> 256 blocks (nk=16 each)
    gemm_bt8<3><<<256, 512, 0, stream>>>(f1b, w2T, w2P0, w2P1, 4096, 1024, 4096, 4, 4);
    reduce4_k<<<4096, 256, 0, stream>>>(w2P0, w2P1, out, out, MN);
}

// Round 21
// 224.093 us; speedup vs baseline: 1.0306x; 1.0306x over previous
//
#include <hip/hip_runtime.h>
#include <hip/hip_bf16.h>
#include <math.h>

#define BDIM 1024
#define HEADS 16
#define HDIM 64
#define LSEQ 2048
#define NBATCH 2
#define DFFDIM 4096
#define QKVN 3072
#define LOG2E 1.44269504f

typedef __bf16 bf16x8_t __attribute__((ext_vector_type(8)));
typedef float f32x4_t __attribute__((ext_vector_type(4)));

__device__ __forceinline__ ushort f2bf(float f) {
    union { __hip_bfloat16 b; ushort u; } cv;
    cv.b = __float2bfloat16(f);
    return cv.u;
}
__device__ __forceinline__ float bf2f(ushort u) {
    union { unsigned int i; float f; } cv;
    cv.i = ((unsigned int)u) << 16;
    return cv.f;
}

// ---------------- batched 4x 1024x1024 transpose (one dispatch) ---------------
__global__ __launch_bounds__(256) void transpose_cvt4(const float* __restrict__ W0,
                                                      const float* __restrict__ W1,
                                                      const float* __restrict__ W2,
                                                      const float* __restrict__ W3,
                                                      ushort* __restrict__ T0,
                                                      ushort* __restrict__ T1,
                                                      ushort* __restrict__ T2,
                                                      ushort* __restrict__ T3) {
    __shared__ ushort tile[32][33];
    const int z = blockIdx.z;
    const float* W = z == 0 ? W0 : z == 1 ? W1 : z == 2 ? W2 : W3;
    ushort* T = z == 0 ? T0 : z == 1 ? T1 : z == 2 ? T2 : T3;
    int bi = blockIdx.y, bj = blockIdx.x;
    int tx = threadIdx.x, ty = threadIdx.y;
#pragma unroll
    for (int r = 0; r < 4; ++r)
        tile[ty + r * 8][tx] = f2bf(W[(size_t)(bi * 32 + ty + r * 8) * 1024 + bj * 32 + tx]);
    __syncthreads();
#pragma unroll
    for (int r = 0; r < 4; ++r)
        T[(size_t)(bj * 32 + ty + r * 8) * 1024 + bi * 32 + tx] = tile[tx][ty + r * 8];
}

// ---------------- merged W1 (1024x4096) + W2 (4096x1024) transpose ------------
// z=0: W1, K=1024, N=4096, bi=blockIdx.y (32), bj=blockIdx.x (128)
// z=1: W2, K=4096, N=1024, bi=blockIdx.x (128), bj=blockIdx.y (32)
__global__ __launch_bounds__(256) void transpose_ff(const float* __restrict__ W1,
                                                    const float* __restrict__ W2,
                                                    ushort* __restrict__ T1,
                                                    ushort* __restrict__ T2) {
    __shared__ ushort tile[32][33];
    const int z = blockIdx.z;
    const float* W = z == 0 ? W1 : W2;
    ushort* T = z == 0 ? T1 : T2;
    const int K = z == 0 ? 1024 : 4096;
    const int N = z == 0 ? 4096 : 1024;
    int bi = z == 0 ? blockIdx.y : blockIdx.x;
    int bj = z == 0 ? blockIdx.x : blockIdx.y;
    int tx = threadIdx.x, ty = threadIdx.y;
#pragma unroll
    for (int r = 0; r < 4; ++r)
        tile[ty + r * 8][tx] = f2bf(W[(size_t)(bi * 32 + ty + r * 8) * N + bj * 32 + tx]);
    __syncthreads();
#pragma unroll
    for (int r = 0; r < 4; ++r)
        T[(size_t)(bj * 32 + ty + r * 8) * K + bi * 32 + tx] = tile[tx][ty + r * 8];
}

// ---------------- RMSNorm: fp32 in -> bf16 out --------------------------------
__global__ __launch_bounds__(256) void rmsnorm_k(const float* __restrict__ x,
                                                 const float* __restrict__ g,
                                                 ushort* __restrict__ out) {
    int row = blockIdx.x;
    int t = threadIdx.x;
    int w = t >> 6, l = t & 63;
    const float4 v = reinterpret_cast<const float4*>(x + (size_t)row * BDIM)[t];
    float ss = v.x * v.x + v.y * v.y + v.z * v.z + v.w * v.w;
#pragma unroll
    for (int m = 1; m <= 32; m <<= 1) ss += __shfl_xor(ss, m);
    __shared__ float wsum[4];
    if (l == 0) wsum[w] = ss;
    __syncthreads();
    float tot = wsum[0] + wsum[1] + wsum[2] + wsum[3];
    float r = rsqrtf(tot * (1.0f / BDIM) + 1e-6f);
    const float4 gv = reinterpret_cast<const float4*>(g)[t];
    ushort4 o;
    o.x = f2bf(v.x * r * gv.x);
    o.y = f2bf(v.y * r * gv.y);
    o.z = f2bf(v.z * r * gv.z);
    o.w = f2bf(v.w * r * gv.w);
    reinterpret_cast<ushort4*>(out + (size_t)row * BDIM)[t] = o;
}

// ---------------- T5 bias table PRE-SCALED by log2e: btab[h][d] ---------------
__global__ void bias_table_k(const float* __restrict__ rel, float* __restrict__ btab) {
    int idx = blockIdx.x * 256 + threadIdx.x;
    if (idx >= HEADS * 4095) return;
    int h = idx / 4095;
    int d = idx % 4095;
    int rp = d - 2047;                 // mem - ctx
    int bucket = rp > 0 ? 16 : 0;
    int rpa = rp < 0 ? -rp : rp;
    if (rpa < 8) {
        bucket += rpa;
    } else {
        int large = 8 + (int)(logf((float)rpa * 0.125f) * (1.0f / logf(16.0f)) * 8.0f);
        bucket += large < 15 ? large : 15;
    }
    btab[idx] = rel[bucket * HEADS + h] * LOG2E;
}

// ---------------- split-K2 reduce + residual + RMSNorm ------------------------
__global__ __launch_bounds__(256) void reduce2_rms(const ushort* __restrict__ parts,
                                                   const float* __restrict__ res,
                                                   const float* __restrict__ g,
                                                   float* __restrict__ out,
                                                   ushort* __restrict__ hout,
                                                   size_t mn) {
    int row = blockIdx.x;
    int t = threadIdx.x;
    int w = t >> 6, l = t & 63;
    size_t i = (size_t)row * BDIM + t * 4;
    float4 r = *(const float4*)(res + i);
    ushort4 a = *(const ushort4*)(parts + i);
    ushort4 b = *(const ushort4*)(parts + mn + i);
    float4 o;
    o.x = r.x + bf2f(a.x) + bf2f(b.x);
    o.y = r.y + bf2f(a.y) + bf2f(b.y);
    o.z = r.z + bf2f(a.z) + bf2f(b.z);
    o.w = r.w + bf2f(a.w) + bf2f(b.w);
    *(float4*)(out + i) = o;
    float ss = o.x * o.x + o.y * o.y + o.z * o.z + o.w * o.w;
#pragma unroll
    for (int m = 1; m <= 32; m <<= 1) ss += __shfl_xor(ss, m);
    __shared__ float wsum[4];
    if (l == 0) wsum[w] = ss;
    __syncthreads();
    float tot = wsum[0] + wsum[1] + wsum[2] + wsum[3];
    float rr = rsqrtf(tot * (1.0f / BDIM) + 1e-6f);
    const float4 gv = reinterpret_cast<const float4*>(g)[t];
    ushort4 h;
    h.x = f2bf(o.x * rr * gv.x);
    h.y = f2bf(o.y * rr * gv.y);
    h.z = f2bf(o.z * rr * gv.z);
    h.w = f2bf(o.w * rr * gv.w);
    reinterpret_cast<ushort4*>(hout + (size_t)row * BDIM)[t] = h;
}

// ---------------- split-K4 reduce: out = res + sum of 4 bf16 partials ---------
__global__ __launch_bounds__(256) void reduce4_k(const ushort* __restrict__ p01,
                                                 const ushort* __restrict__ p23,
                                                 const float* __restrict__ res,
                                                 float* __restrict__ out,
                                                 size_t mn) {
    size_t i = ((size_t)blockIdx.x * 256 + threadIdx.x) * 4;
    float4 r = *(const float4*)(res + i);
    ushort4 a = *(const ushort4*)(p01 + i);
    ushort4 b = *(const ushort4*)(p01 + mn + i);
    ushort4 c = *(const ushort4*)(p23 + i);
    ushort4 d = *(const ushort4*)(p23 + mn + i);
    float4 o;
    o.x = r.x + bf2f(a.x) + bf2f(b.x) + bf2f(c.x) + bf2f(d.x);
    o.y = r.y + bf2f(a.y) + bf2f(b.y) + bf2f(c.y) + bf2f(d.y);
    o.z = r.z + bf2f(a.z) + bf2f(b.z) + bf2f(c.z) + bf2f(d.z);
    o.w = r.w + bf2f(a.w) + bf2f(b.w) + bf2f(c.w) + bf2f(d.w);
    *(float4*)(out + i) = o;
}

// ---------------- bf16 GEMM, B pre-transposed (Bt is N x K), 1D grid + XCD swz
// m97 single-buffer 2-barrier structure + T2 swizzle. Optional split-K.
// MODE 0: bf16 ; MODE 1: f32 res+ ; MODE 2: relu ; MODE 3: bf16 partial ;
// MODE 4: QKV fused-vtrans (V cols transposed into vtb; Q cols scaled by log2e)
template <int MODE, int TM, int TN>
__global__ __launch_bounds__(256) void gemm_bt(const ushort* __restrict__ A,
                                               const ushort* __restrict__ Bt,
                                               void* Cout, const float* res,
                                               ushort* __restrict__ vtb,
                                               int M, int N, int K, int nbx, int nkc) {
    __shared__ __align__(16) ushort As[TM * 64];
    __shared__ __align__(16) ushort Bs[TN * 64];
    constexpr int MF = TM / 32, NF = TN / 32;
    const int nwg = gridDim.x;
    const int bid = blockIdx.x;
    const int swz = (bid & 7) * (nwg >> 3) + (bid >> 3);   // nwg % 8 == 0 always
    const int nxy = nwg / nkc;
    const int chunk = swz / nxy;
    const int bxy = swz % nxy;
    const int bx = bxy % nbx, by = bxy / nbx;
    const int Kc = K / nkc;
    const int kbeg = chunk * Kc;
    const int tid = threadIdx.x;
    const int w = tid >> 6, l = tid & 63;
    const int wm = w >> 1, wn = w & 1;
    const int rowA0 = by * TM;
    const int colB0 = bx * TN;
    const int lr = l >> 3;
    const int scs = ((l & 7) ^ lr) * 8;        // pre-swizzled source col (ushorts)
    const int c = l & 15, gq = l >> 4;
    const int rswz = (c & 7) * 8;              // read-side XOR (row&7 == c&7)
    f32x4_t acc[MF][NF] = {};

    auto stage = [&](int k0) {
#pragma unroll
        for (int i = 0; i < TM / 32; ++i) {
            int r = i * 32 + w * 8;
            __builtin_amdgcn_global_load_lds(
                (const __attribute__((address_space(1))) uint32_t*)(A + (size_t)(rowA0 + r + lr) * K + kbeg + k0 + scs),
                (__attribute__((address_space(3))) uint32_t*)(&As[r * 64]), 16, 0, 0);
        }
#pragma unroll
        for (int i = 0; i < TN / 32; ++i) {
            int r = i * 32 + w * 8;
            __builtin_amdgcn_global_load_lds(
                (const __attribute__((address_space(1))) uint32_t*)(Bt + (size_t)(colB0 + r + lr) * K + kbeg + k0 + scs),
                (__attribute__((address_space(3))) uint32_t*)(&Bs[r * 64]), 16, 0, 0);
        }
    };

    const int nk = Kc >> 6;
    for (int kt = 0; kt < nk; ++kt) {
        __syncthreads();           // previous tile's readers done
        stage(kt << 6);
        __syncthreads();           // vmcnt drained: tile visible
#pragma unroll
        for (int kk = 0; kk < 2; ++kk) {
            bf16x8_t av[MF], bv[NF];
#pragma unroll
            for (int mf = 0; mf < MF; ++mf)
                av[mf] = *(const bf16x8_t*)&As[(wm * (TM / 2) + mf * 16 + c) * 64 + ((kk * 32 + gq * 8) ^ rswz)];
#pragma unroll
            for (int nf = 0; nf < NF; ++nf)
                bv[nf] = *(const bf16x8_t*)&Bs[(wn * (TN / 2) + nf * 16 + c) * 64 + ((kk * 32 + gq * 8) ^ rswz)];
#pragma unroll
            for (int mf = 0; mf < MF; ++mf)
#pragma unroll
                for (int nf = 0; nf < NF; ++nf)
                    acc[mf][nf] = __builtin_amdgcn_mfma_f32_16x16x32_bf16(av[mf], bv[nf], acc[mf][nf], 0, 0, 0);
        }
    }
    if (MODE == 4 && colB0 >= 2048) {
        // V block: store transposed into vtb[(b*16+h)*64+hd][key]
#pragma unroll
        for (int mf = 0; mf < MF; ++mf) {
#pragma unroll
            for (int nf = 0; nf < NF; ++nf) {
                int col = colB0 + wn * (TN / 2) + nf * 16 + c;
                int v = col - 2048;
                int hh = v >> 6, hd = v & 63;
                int row0 = rowA0 + wm * (TM / 2) + mf * 16 + gq * 4;
                int bb = row0 >> 11, key = row0 & 2047;
                ushort4 ov;
                ov.x = f2bf(acc[mf][nf][0]);
                ov.y = f2bf(acc[mf][nf][1]);
                ov.z = f2bf(acc[mf][nf][2]);
                ov.w = f2bf(acc[mf][nf][3]);
                *(ushort4*)(vtb + ((size_t)((bb * 16 + hh) * 64 + hd)) * 2048 + key) = ov;
            }
        }
        return;
    }
#pragma unroll
    for (int mf = 0; mf < MF; ++mf) {
#pragma unroll
        for (int nf = 0; nf < NF; ++nf) {
#pragma unroll
            for (int i = 0; i < 4; ++i) {
                int row = rowA0 + wm * (TM / 2) + mf * 16 + gq * 4 + i;
                int col = colB0 + wn * (TN / 2) + nf * 16 + c;
                size_t idx = (size_t)row * N + col;
                float vv = acc[mf][nf][i];
                if (MODE == 0 || MODE == 4) {
                    if (MODE == 4 && col < 1024) vv *= LOG2E;   // pre-scale Q for exp2 softmax
                    ((ushort*)Cout)[idx] = f2bf(vv);
                } else if (MODE == 1) {
                    ((float*)Cout)[idx] = res[idx] + vv;
                } else if (MODE == 2) {
                    ((ushort*)Cout)[idx] = f2bf(vv > 0.f ? vv : 0.f);
                } else {
                    ((ushort*)Cout)[(size_t)chunk * M * N + idx] = f2bf(vv);
                }
            }
        }
    }
}

// ---------------- 8-phase 256x256 GEMM (T3+T4+T5), 8 waves, 128KB LDS ---------
// Next-tile staging front-loaded into phases 0/1 so the K-tile-boundary
// vmcnt(0) has >= 2 phases of compute cover. MODE 2: relu; MODE 3: split-K
// partials (chunks 0,1 -> Cout, chunks 2,3 -> Cout2).
template <int MODE>
__global__ __launch_bounds__(512, 1) void gemm_bt8(const ushort* __restrict__ A,
                                                   const ushort* __restrict__ Bt,
                                                   void* Cout, void* Cout2,
                                                   int M, int N, int K, int nbx, int nkc) {
    __shared__ __align__(16) ushort As[2][256 * 64];
    __shared__ __align__(16) ushort Bs[2][256 * 64];
    const int nwg = gridDim.x;
    const int bid = blockIdx.x;
    const int swz = (bid & 7) * (nwg >> 3) + (bid >> 3);
    const int nxy = nwg / nkc;
    const int chunk = swz / nxy;
    const int bxy = swz % nxy;
    const int bx = bxy % nbx, by = bxy / nbx;
    const int Kc = K / nkc;
    const int kbeg = chunk * Kc;
    const int tid = threadIdx.x;
    const int w = tid >> 6, l = tid & 63;
    const int wm = w >> 2, wn = w & 3;          // 2 x 4 wave grid
    const int rowA0 = by * 256, colB0 = bx * 256;
    const int st_r = tid >> 3;                  // 0..63 row within chunk
    const int scs = ((l & 7) ^ (st_r & 7)) * 8; // pre-swizzled source col
    const int c = l & 15, gq = l >> 4;
    const int rswz = (c & 7) * 8;
    f32x4_t acc[8][4] = {};

    auto stageChunk = [&](int buf, int k0, int q) {
        __builtin_amdgcn_global_load_lds(
            (const __attribute__((address_space(1))) uint32_t*)(A + (size_t)(rowA0 + q * 64 + st_r) * K + kbeg + k0 + scs),
            (__attribute__((address_space(3))) uint32_t*)(&As[buf][(q * 64 + w * 8) * 64]), 16, 0, 0);
        __builtin_amdgcn_global_load_lds(
            (const __attribute__((address_space(1))) uint32_t*)(Bt + (size_t)(colB0 + q * 64 + st_r) * K + kbeg + k0 + scs),
            (__attribute__((address_space(3))) uint32_t*)(&Bs[buf][(q * 64 + w * 8) * 64]), 16, 0, 0);
    };

    const int nk = Kc >> 6;
    stageChunk(0, 0, 0);
    stageChunk(0, 0, 1);
    stageChunk(0, 0, 2);
    stageChunk(0, 0, 3);
    asm volatile("s_waitcnt vmcnt(0)" ::: "memory");
    __builtin_amdgcn_s_barrier();
    __builtin_amdgcn_sched_barrier(0);

    for (int k = 0; k < nk; ++k) {
        const int cur = k & 1;
        const ushort* Ab = &As[cur][0];
        const ushort* Bb = &Bs[cur][0];
#pragma unroll
        for (int q = 0; q < 4; ++q) {
            const int mh = q >> 1, nh = q & 1;
            bf16x8_t av[4][2], bv[2][2];
#pragma unroll
            for (int mf = 0; mf < 4; ++mf)
#pragma unroll
                for (int kk = 0; kk < 2; ++kk)
                    av[mf][kk] = *(const bf16x8_t*)&Ab[(wm * 128 + mh * 64 + mf * 16 + c) * 64 + ((kk * 32 + gq * 8) ^ rswz)];
#pragma unroll
            for (int nf = 0; nf < 2; ++nf)
#pragma unroll
                for (int kk = 0; kk < 2; ++kk)
                    bv[nf][kk] = *(const bf16x8_t*)&Bb[(wn * 64 + nh * 32 + nf * 16 + c) * 64 + ((kk * 32 + gq * 8) ^ rswz)];
            if (k + 1 < nk) {
                if (q == 0) { stageChunk(cur ^ 1, (k + 1) << 6, 0); stageChunk(cur ^ 1, (k + 1) << 6, 1); }
                else if (q == 1) { stageChunk(cur ^ 1, (k + 1) << 6, 2); stageChunk(cur ^ 1, (k + 1) << 6, 3); }
            }
            __builtin_amdgcn_s_barrier();
            __builtin_amdgcn_sched_barrier(0);
            __builtin_amdgcn_s_setprio(1);
#pragma unroll
            for (int kk = 0; kk < 2; ++kk)
#pragma unroll
                for (int mf = 0; mf < 4; ++mf)
#pragma unroll
                    for (int nf = 0; nf < 2; ++nf)
                        acc[mh * 4 + mf][nh * 2 + nf] = __builtin_amdgcn_mfma_f32_16x16x32_bf16(
                            av[mf][kk], bv[nf][kk], acc[mh * 4 + mf][nh * 2 + nf], 0, 0, 0);
            __builtin_amdgcn_s_setprio(0);
            if (q == 3 && k + 1 < nk)
                asm volatile("s_waitcnt vmcnt(0)" ::: "memory");
            __builtin_amdgcn_s_barrier();
            __builtin_amdgcn_sched_barrier(0);
        }
    }
    ushort* dst;
    if (MODE == 3)
        dst = (ushort*)(chunk < 2 ? Cout : Cout2) + (size_t)(chunk & 1) * M * N;
    else
        dst = (ushort*)Cout;
#pragma unroll
    for (int am = 0; am < 8; ++am) {
#pragma unroll
        for (int an = 0; an < 4; ++an) {
#pragma unroll
            for (int i = 0; i < 4; ++i) {
                int row = rowA0 + wm * 128 + am * 16 + gq * 4 + i;
                int col = colB0 + wn * 64 + an * 16 + c;
                size_t idx = (size_t)row * N + col;
                float vv = acc[am][an][i];
                if (MODE == 2) {
                    dst[idx] = f2bf(vv > 0.f ? vv : 0.f);
                } else {
                    dst[idx] = f2bf(vv);
                }
            }
        }
    }
}

// ---------------- flash attention: 8-wave, LDS dbuf, exp2 softmax, XCD-affine -
// 1D grid of 512: xcd = bid&7 owns 4 heads x 16 q-tiles -> per-XCD K/V working
// set = 2MB fits the 4MB per-XCD L2; K/V HBM-fetched once, re-reads L2-hit.
__global__ __launch_bounds__(512) void attn_fwd(const ushort* __restrict__ qkv,
                                                const ushort* __restrict__ vT,
                                                const float* __restrict__ btab,
                                                ushort* __restrict__ ob) {
    const int tid = threadIdx.x, w = tid >> 6, l = tid & 63;
    const int bid = blockIdx.x;
    const int xcd = bid & 7, pos = bid >> 3;
    const int bh = (xcd << 2) + (pos >> 4);    // 4 heads per XCD
    const int qt = pos & 15;
    const int b = bh >> 4, h = bh & 15;
    __shared__ __align__(16) ushort Ks[2][64 * 64];    // [key][hd ^ swz]
    __shared__ __align__(16) ushort Vs[2][64 * 64];    // [hd][key ^ swz]
    __shared__ __align__(16) ushort Pl[8][16 * 72];    // per-wave P[q][key], stride 72
    const int q0 = qt * 128 + w * 16;
    const int c = l & 15, g = l >> 4;
    const size_t rowbase = (size_t)b * LSEQ * QKVN;
    const ushort* qp = qkv + rowbase + h * HDIM;
    const ushort* kp = qkv + rowbase + BDIM + h * HDIM;
    const ushort* vtp = vT + (size_t)bh * HDIM * LSEQ;
    const int sr = tid >> 3;                     // 0..63
    const int scs = ((l & 7) ^ (l >> 3)) * 8;    // swizzled source col (ushorts)
    const float* btq4 = btab + h * 4095 + 2047 - (q0 + c) + g * 4;

    bf16x8_t aq[2];  // B-operand: Q[q0+c][kk*32 + g*8 + j] (pre-scaled by log2e)
#pragma unroll
    for (int kk = 0; kk < 2; ++kk)
        aq[kk] = *(const bf16x8_t*)(qp + (size_t)(q0 + c) * QKVN + kk * 32 + g * 8);

    float lrow = 0.f;
    f32x4_t o[4] = {};   // O^T[hd = hf*16 + g*4 + i][q0+c]
    f32x4_t s[4];        // S^T[key0 + nf*16 + g*4 + i][q0+c]

    auto stage = [&](int buf, int key0) {
        __builtin_amdgcn_global_load_lds(
            (const __attribute__((address_space(1))) uint32_t*)(kp + (size_t)(key0 + sr) * QKVN + scs),
            (__attribute__((address_space(3))) uint32_t*)(&Ks[buf][(w * 8) * 64]), 16, 0, 0);
        __builtin_amdgcn_global_load_lds(
            (const __attribute__((address_space(1))) uint32_t*)(vtp + (size_t)sr * LSEQ + key0 + scs),
            (__attribute__((address_space(3))) uint32_t*)(&Vs[buf][(w * 8) * 64]), 16, 0, 0);
    };
    auto loadBias = [&](int key0) {
#pragma unroll
        for (int nf = 0; nf < 4; ++nf)
#pragma unroll
            for (int i = 0; i < 4; ++i)
                s[nf][i] = btq4[key0 + nf * 16 + i];
    };

    stage(0, 0);
    loadBias(0);
    int cur = 0;

    ushort* Pw = Pl[w];
    const int rswz = (c & 7) << 3;   // read-side XOR for rows nf*16+c / hf*16+c
    for (int kt = 0; kt < 32; ++kt) {
        __syncthreads();   // buf[cur] staged (vmcnt drained at barrier); buf[cur^1] free
        if (kt < 31) stage(cur ^ 1, kt * 64 + 64);
        // 1. S^T = bias + K Q^T  (all pre-scaled by log2e)
#pragma unroll
        for (int kk = 0; kk < 2; ++kk)
#pragma unroll
            for (int nf = 0; nf < 4; ++nf) {
                bf16x8_t kf = *(const bf16x8_t*)&Ks[cur][(nf * 16 + c) * 64 + ((kk * 32 + g * 8) ^ rswz)];
                s[nf] = __builtin_amdgcn_mfma_f32_16x16x32_bf16(kf, aq[kk], s[nf], 0, 0, 0);
            }
        // 2. P = exp2(s) directly, per-lane row-sum
        float rs = 0.f;
        union { ushort us[4]; uint2 u2; } pk[4];
#pragma unroll
        for (int nf = 0; nf < 4; ++nf)
#pragma unroll
            for (int i = 0; i < 4; ++i) {
                float pv = __builtin_amdgcn_exp2f(s[nf][i]);
                rs += pv;
                pk[nf].us[i] = f2bf(pv);
            }
        // 3. prefetch bias(kt+1) into accumulator (s is dead now; L1-resident)
        if (kt < 31) loadBias(kt * 64 + 64);
        lrow += rs;
        // 4. P -> per-wave LDS [q=c][key], packed b64 writes; wave-local
#pragma unroll
        for (int nf = 0; nf < 4; ++nf)
            *(uint2*)&Pw[c * 72 + nf * 16 + g * 4] = pk[nf].u2;
        bf16x8_t pa[2];
#pragma unroll
        for (int kk = 0; kk < 2; ++kk)
            pa[kk] = *(const bf16x8_t*)&Pw[c * 72 + kk * 32 + g * 8];
        // 5. O^T += V^T P^T
#pragma unroll
        for (int kk = 0; kk < 2; ++kk)
#pragma unroll
            for (int hf = 0; hf < 4; ++hf) {
                bf16x8_t vf = *(const bf16x8_t*)&Vs[cur][(hf * 16 + c) * 64 + ((kk * 32 + g * 8) ^ rswz)];
                o[hf] = __builtin_amdgcn_mfma_f32_16x16x32_bf16(vf, pa[kk], o[hf], 0, 0, 0);
            }
        cur ^= 1;
    }
    // deferred cross-lane row-sum (q = c lives in lanes c, c+16, c+32, c+48)
    lrow += __shfl_xor(lrow, 16);
    lrow += __shfl_xor(lrow, 32);
    const float inv = 1.f / lrow;
    ushort* orow = ob + (size_t)(b * LSEQ + q0 + c) * BDIM + h * HDIM + g * 4;
#pragma unroll
    for (int hf = 0; hf < 4; ++hf) {
        ushort4 ov;
        ov.x = f2bf(o[hf][0] * inv);
        ov.y = f2bf(o[hf][1] * inv);
        ov.z = f2bf(o[hf][2] * inv);
        ov.w = f2bf(o[hf][3] * inv);
        *(ushort4*)(orow + hf * 16) = ov;
    }
}

extern "C" void kernel_launch(void* const* d_in, const int* in_sizes, int n_in,
                              void* d_out, int out_size, void* d_ws, size_t ws_size,
                              hipStream_t stream) {
    const float* x   = (const float*)d_in[0];
    const float* Wq  = (const float*)d_in[1];
    const float* Wk  = (const float*)d_in[2];
    const float* Wv  = (const float*)d_in[3];
    const float* Wo  = (const float*)d_in[4];
    const float* W1  = (const float*)d_in[5];
    const float* W2  = (const float*)d_in[6];
    const float* g1  = (const float*)d_in[7];
    const float* g2  = (const float*)d_in[8];
    const float* rel = (const float*)d_in[9];
    float* out = (float*)d_out;

    char* ws = (char*)d_ws;
    const size_t MB = 1024 * 1024;
    ushort* wqkvT = (ushort*)(ws + 0 * MB);    // 6MB (dead after QKV)
    ushort* woT   = (ushort*)(ws + 6 * MB);    // 2MB (dead after Wo gemm)
    ushort* w1T   = (ushort*)(ws + 8 * MB);    // 8MB (dead after FF1)
    ushort* w2T   = (ushort*)(ws + 16 * MB);   // 8MB (live through W2 gemm)
    float*  btab  = (float*)(ws + 24 * MB);    // 256KB
    ushort* hbuf  = (ushort*)(ws + 25 * MB);   // 8MB: h, then attn_out, then h2
    ushort* qkvb  = (ushort*)(ws + 33 * MB);   // 24MB (dead after attn)
    ushort* woP   = (ushort*)(ws + 33 * MB);   // 16MB Wo partials (over dead qkv)
    ushort* f1b   = (ushort*)(ws + 33 * MB);   // 32MB FF1 out (33-65)
    ushort* vTb   = (ushort*)(ws + 57 * MB);   // 8MB (dead after attn)
    ushort* w2P0  = (ushort*)(ws + 0 * MB);    // 16MB W2 partials 0,1 (dead weights)
    ushort* w2P1  = (ushort*)(ws + 65 * MB);   // 16MB W2 partials 2,3 (65-81)
    (void)in_sizes; (void)n_in; (void)out_size; (void)ws_size;

    const size_t MN = (size_t)4096 * 1024;
    dim3 tb(32, 8);
    transpose_cvt4<<<dim3(32, 32, 4), tb, 0, stream>>>(Wq, Wk, Wv, Wo,
        wqkvT, wqkvT + 1024 * 1024, wqkvT + 2048 * 1024, woT);
    transpose_ff<<<dim3(128, 32, 2), tb, 0, stream>>>(W1, W2, w1T, w2T);
    bias_table_k<<<256, 256, 0, stream>>>(rel, btab);

    rmsnorm_k<<<4096, 256, 0, stream>>>(x, g1, hbuf);
    // QKV: 4096 x 3072 x 1024, 128x128 -> 768 blocks; V transposed, Q pre-scaled
    gemm_bt<4, 128, 128><<<768, 256, 0, stream>>>(hbuf, wqkvT, qkvb, nullptr, vTb, 4096, QKVN, 1024, 24, 1);
    attn_fwd<<<512, 512, 0, stream>>>(qkvb, vTb, btab, hbuf);
    // Wo: 4096 x 1024 x 1024, 128x128, split-K=2 -> 512 blocks
    gemm_bt<3, 128, 128><<<512, 256, 0, stream>>>(hbuf, woT, woP, nullptr, nullptr, 4096, 1024, 1024, 8, 2);
    // fused: out = x + sum(partials); hbuf = rmsnorm(out)*g2
    reduce2_rms<<<4096, 256, 0, stream>>>(woP, x, g2, out, hbuf, MN);
    // FF1: 4096 x 4096 x 1024, 256x256 8-phase -> 256 blocks (1/CU), relu -> bf16
    gemm_bt8<2><<<256, 512, 0, stream>>>(hbuf, w1T, f1b, nullptr, 4096, DFFDIM, 1024, 16, 1);
    // W2: 4096 x 1024 x 4096, 256x256 8-phase, split-K=4 -> 256 blocks (nk=16 each)
    gemm_bt8<3><<<256, 512, 0, stream>>>(f1b, w2T, w2P0, w2P1, 4096, 1024, 4096, 4, 4);
    reduce4_k<<<4096, 256, 0, stream>>>(w2P0, w2P1, out, out, MN);
}